// Round 1
// baseline (70.233 us; speedup 1.0000x reference)
//
#include <hip/hip_runtime.h>

// 3x3 cross-correlation, padding=1, NCHW fp32.
// out[b,o,h,w] = bias[o] + sum_{ky,kx,c} comb[o,(ky*3+kx)*16+c] * x[b,c,h+ky-1,w+kx-1]
// B=4, C=16, O=16, H=450, W=480.
//
// Strategy (round 1, fp32 VALU):
//  - each thread computes 4 consecutive w pixels x 16 output channels (64 acc)
//  - loop (ky, c): 6 x values (float4 + 2 scalars) amortized over 192 FMAs
//  - weights repacked into LDS as [ky][c][kx][o] (o contiguous) -> ds_read_b128
//    broadcast (wave-uniform address, conflict-free)

#define HH 450
#define WW 480
#define BB 4
#define CC 16
#define OO 16
#define WQ (WW / 4)              // 120 quads per row
#define NT (BB * HH * WQ)        // 216000 threads of work

__global__ __launch_bounds__(256) void flow_conv_kernel(
    const float* __restrict__ x, const float* __restrict__ comb,
    const float* __restrict__ bias, float* __restrict__ out)
{
    __shared__ __align__(16) float wlds[3 * CC * 3 * OO]; // [ky][c][kx][o] = 2304 floats

    // Stage + repack weights: wlds[((ky*16+c)*3+kx)*16+o] = comb[o*144 + (ky*3+kx)*16 + c]
    for (int idx = threadIdx.x; idx < 3 * CC * 3 * OO; idx += 256) {
        int o    = idx & 15;
        int kx   = (idx >> 4) % 3;
        int rest = idx / 48;          // ky*16 + c
        int c    = rest & 15;
        int ky   = rest >> 4;
        wlds[idx] = comb[o * 144 + (ky * 3 + kx) * CC + c];
    }
    __syncthreads();

    int tid = blockIdx.x * 256 + threadIdx.x;
    if (tid >= NT) return;

    int wq = tid % WQ;
    int t2 = tid / WQ;
    int h  = t2 % HH;
    int b  = t2 / HH;
    int w  = wq * 4;

    float acc[OO][4];
    #pragma unroll
    for (int o = 0; o < OO; ++o) {
        float bv = bias[o];
        acc[o][0] = bv; acc[o][1] = bv; acc[o][2] = bv; acc[o][3] = bv;
    }

    const float* xb = x + (size_t)b * CC * HH * WW;

    #pragma unroll 1
    for (int ky = 0; ky < 3; ++ky) {
        int hy = h + ky - 1;
        bool hok = (unsigned)hy < (unsigned)HH;
        const float* xrow = xb + (size_t)hy * WW + w;

        #pragma unroll 1
        for (int c = 0; c < CC; ++c) {
            // xv[j] = x[b,c,hy, w + j - 1], zero-padded
            float xv[6];
            if (hok) {
                const float* rp = xrow + (size_t)c * (HH * WW);
                float4 m = *(const float4*)rp;          // w .. w+3 (16B aligned)
                xv[0] = (w > 0)      ? rp[-1] : 0.0f;
                xv[1] = m.x; xv[2] = m.y; xv[3] = m.z; xv[4] = m.w;
                xv[5] = (w < WW - 4) ? rp[4]  : 0.0f;
            } else {
                #pragma unroll
                for (int j = 0; j < 6; ++j) xv[j] = 0.0f;
            }

            const float4* w4 = (const float4*)&wlds[(ky * CC + c) * 48];
            #pragma unroll
            for (int kx = 0; kx < 3; ++kx) {
                #pragma unroll
                for (int oq = 0; oq < 4; ++oq) {
                    float4 wv = w4[kx * 4 + oq];
                    float wf[4] = {wv.x, wv.y, wv.z, wv.w};
                    #pragma unroll
                    for (int j = 0; j < 4; ++j) {
                        int o = oq * 4 + j;
                        #pragma unroll
                        for (int p = 0; p < 4; ++p)
                            acc[o][p] = fmaf(wf[j], xv[p + kx], acc[o][p]);
                    }
                }
            }
        }
    }

    float* ob = out + (size_t)b * OO * HH * WW + (size_t)h * WW + w;
    #pragma unroll
    for (int o = 0; o < OO; ++o) {
        float4 st = make_float4(acc[o][0], acc[o][1], acc[o][2], acc[o][3]);
        *(float4*)(ob + (size_t)o * (HH * WW)) = st;
    }
}

extern "C" void kernel_launch(void* const* d_in, const int* in_sizes, int n_in,
                              void* d_out, int out_size, void* d_ws, size_t ws_size,
                              hipStream_t stream) {
    const float* x    = (const float*)d_in[0];
    const float* comb = (const float*)d_in[1];
    const float* bias = (const float*)d_in[2];
    float* out        = (float*)d_out;

    int nblocks = (NT + 255) / 256;  // 844
    flow_conv_kernel<<<nblocks, 256, 0, stream>>>(x, comb, bias, out);
}